// Round 5
// baseline (287.325 us; speedup 1.0000x reference)
//
#include <hip/hip_runtime.h>

#define N_ 8192
#define INF_ 512
#define OUTF_ 256
#define KVSPLIT 8
#define BK 32
#define BQ 128
#define NTILES (N_ / KVSPLIT / BK)   // 32

typedef float f32x4 __attribute__((ext_vector_type(4)));
typedef __bf16 bf16x8 __attribute__((ext_vector_type(8)));

__device__ __forceinline__ unsigned short f2bf(float f) {
  union { float f; unsigned u; } v; v.f = f;
  unsigned r = v.u + 0x7fffu + ((v.u >> 16) & 1u);
  return (unsigned short)(r >> 16);
}
__device__ __forceinline__ float bf2f(unsigned short u) {
  union { unsigned u; float f; } v; v.u = ((unsigned)u) << 16;
  return v.f;
}

// ---------------------------------------------------------------------------
// Kernel 0: prep. x -> xhi+xlo (bf16 split), W -> WT (bf16, [col][k]).
// ---------------------------------------------------------------------------
__global__ __launch_bounds__(256) void k_prep(
    const float* __restrict__ x, const float* __restrict__ W,
    unsigned short* __restrict__ xhi, unsigned short* __restrict__ xlo,
    unsigned short* __restrict__ WT)
{
  int idx = blockIdx.x * 256 + threadIdx.x;     // 1M threads, one float4 each
  float4 v = ((const float4*)x)[idx];
  float f[4] = {v.x, v.y, v.z, v.w};
  unsigned short h[4], lo[4];
#pragma unroll
  for (int j = 0; j < 4; ++j) {
    h[j] = f2bf(f[j]);
    lo[j] = f2bf(f[j] - bf2f(h[j]));
  }
  *(uint2*)&xhi[idx * 4] = *(uint2*)h;
  *(uint2*)&xlo[idx * 4] = *(uint2*)lo;
  if (idx < INF_ * OUTF_) {
    int c = idx & (OUTF_ - 1);
    int k = idx >> 8;
    WT[c * INF_ + k] = f2bf(W[k * OUTF_ + c]);
  }
}

// ---------------------------------------------------------------------------
// Kernel 1: h = x @ W via bf16 MFMA (hi/lo split for x). No LDS.
// ---------------------------------------------------------------------------
__global__ __launch_bounds__(256) void k_gemm_h(
    const unsigned short* __restrict__ xhi, const unsigned short* __restrict__ xlo,
    const unsigned short* __restrict__ WT,
    unsigned short* __restrict__ hK, unsigned short* __restrict__ hT)
{
  const int tid = threadIdx.x;
  const int w = tid >> 6, l = tid & 63, g = l >> 4, li = l & 15;
  const int r0 = blockIdx.x * 64 + w * 16;
  const int c0 = blockIdx.y * 64;

  f32x4 acc[4];
  const f32x4 z4 = {0.f, 0.f, 0.f, 0.f};
#pragma unroll
  for (int n = 0; n < 4; ++n) acc[n] = z4;

  const unsigned short* xh = xhi + (size_t)(r0 + li) * INF_ + g * 8;
  const unsigned short* xl = xlo + (size_t)(r0 + li) * INF_ + g * 8;
  const unsigned short* wt = WT + (size_t)(c0 + li) * INF_ + g * 8;

#pragma unroll 4
  for (int kc = 0; kc < 16; ++kc) {
    bf16x8 Ah = *(const bf16x8*)(xh + kc * 32);
    bf16x8 Al = *(const bf16x8*)(xl + kc * 32);
#pragma unroll
    for (int n = 0; n < 4; ++n) {
      bf16x8 Bn = *(const bf16x8*)(wt + (size_t)n * 16 * INF_ + kc * 32);
      acc[n] = __builtin_amdgcn_mfma_f32_16x16x32_bf16(Ah, Bn, acc[n], 0, 0, 0);
      acc[n] = __builtin_amdgcn_mfma_f32_16x16x32_bf16(Al, Bn, acc[n], 0, 0, 0);
    }
  }
#pragma unroll
  for (int n = 0; n < 4; ++n)
#pragma unroll
    for (int s = 0; s < 4; ++s) {
      unsigned short b = f2bf(acc[n][s]);
      int row = r0 + 4 * g + s;
      int col = c0 + n * 16 + li;
      hK[(size_t)row * OUTF_ + col] = b;
      hT[(size_t)col * N_ + row] = b;
    }
}

// ---------------------------------------------------------------------------
// Kernel 2: fused masked attention.
//  - K in LDS (dbuf, gload_lds, XOR-swizzled)
//  - adj in LDS (dbuf, gload_lds, XOR-swizzled 16B groups)
//  - V read DIRECT from global hT (per-XCD L2-resident slab)
//  - swapped QK (St = K·Q^T), in-register P via cvt_pk + shfl
//  4 waves x 32 q-rows, BK=32, 64 KB LDS -> 2 blocks/CU.
// ---------------------------------------------------------------------------
__global__ __launch_bounds__(256, 2) void k_attn(
    const unsigned short* __restrict__ hK, const unsigned short* __restrict__ hT,
    const int* __restrict__ adj, const float* __restrict__ a,
    unsigned short* __restrict__ Opart, float* __restrict__ lsum)
{
  __shared__ __align__(16) unsigned char smem[65536];
  unsigned char* KA = smem;
  unsigned char* KB = smem + 16384;
  unsigned char* AA = smem + 32768;
  unsigned char* AB = smem + 49152;

  const int tid = threadIdx.x;
  const int w = tid >> 6, l = tid & 63, g = l >> 4, li = l & 15;
  const int bid = blockIdx.x;
  const int split = bid & 7;          // XCD-aligned KV split
  const int qblk = (bid >> 3) * BQ;
  const int qrw = qblk + w * 32;
  const int jb = split * (N_ / KVSPLIT);
  const float SCALE = 0.18033688011112042f;  // log2(e)/8

  // K staging source offsets (16B chunks)
  int offK[4];
  const int* srcA[4];
#pragma unroll
  for (int p = 0; p < 4; ++p) {
    int ch = tid + p * 256;
    int rK = ch >> 5, cK = ch & 31;
    offK[p] = rK * OUTF_ + ((cK ^ (rK & 7)) * 8);
    int rA = ch >> 3, cA = ch & 7;
    srcA[p] = adj + (size_t)(qblk + rA) * N_ + ((cA ^ (rA & 7)) * 4);
  }
  // LDS read offsets
  int cxor[8];
#pragma unroll
  for (int kt = 0; kt < 8; ++kt) cxor[kt] = ((kt * 4 + g) ^ (li & 7)) * 16;
  const int kbase = li * 512;
  const int abase = (w * 32 + li) * 128;
  int aswz[2];
#pragma unroll
  for (int jt = 0; jt < 2; ++jt) aswz[jt] = ((jt * 4 + g) ^ (li & 7)) * 16;

  // V direct-load base: lane (g,li) reads hT[d = dt*16+li][j0 + 8g ..]
  const unsigned short* vb = hT + (size_t)li * N_ + 8 * g + jb;

  // Q fragments: q = h * a
  bf16x8 Qf[2][8];
#pragma unroll
  for (int rg = 0; rg < 2; ++rg) {
    const unsigned short* hp = hK + (size_t)(qrw + rg * 16 + li) * OUTF_;
#pragma unroll
    for (int kt = 0; kt < 8; ++kt) {
      bf16x8 hv = *(const bf16x8*)(hp + kt * 32 + g * 8);
      const float* ap = a + kt * 32 + g * 8;
      float4 a0 = *(const float4*)ap;
      float4 a1 = *(const float4*)(ap + 4);
      bf16x8 q;
      q[0] = (__bf16)((float)hv[0] * a0.x);
      q[1] = (__bf16)((float)hv[1] * a0.y);
      q[2] = (__bf16)((float)hv[2] * a0.z);
      q[3] = (__bf16)((float)hv[3] * a0.w);
      q[4] = (__bf16)((float)hv[4] * a1.x);
      q[5] = (__bf16)((float)hv[5] * a1.y);
      q[6] = (__bf16)((float)hv[6] * a1.z);
      q[7] = (__bf16)((float)hv[7] * a1.w);
      Qf[rg][kt] = q;
    }
  }

  f32x4 O[2][16];
  const f32x4 z4 = {0.f, 0.f, 0.f, 0.f};
#pragma unroll
  for (int rg = 0; rg < 2; ++rg)
#pragma unroll
    for (int dt = 0; dt < 16; ++dt) O[rg][dt] = z4;
  float lp[2] = {0.f, 0.f};

  const bool lo32 = (l < 32);
  const bool geven = ((l & 16) == 0);

#define STAGEKA(tt, Kd, Ad) do { \
    const int _j0 = jb + (tt) * BK; \
    const unsigned short* _hk = hK + (size_t)_j0 * OUTF_; \
    _Pragma("unroll") \
    for (int p = 0; p < 4; ++p) \
      __builtin_amdgcn_global_load_lds( \
        (const __attribute__((address_space(1))) void*)(_hk + offK[p]), \
        (__attribute__((address_space(3))) void*)((Kd) + (p * 256 + w * 64) * 16), 16, 0, 0); \
    _Pragma("unroll") \
    for (int p = 0; p < 4; ++p) \
      __builtin_amdgcn_global_load_lds( \
        (const __attribute__((address_space(1))) void*)(srcA[p] + _j0), \
        (__attribute__((address_space(3))) void*)((Ad) + (p * 256 + w * 64) * 16), 16, 0, 0); \
  } while (0)

  STAGEKA(0, KA, AA);
  __syncthreads();

#pragma unroll 1
  for (int t = 0; t < NTILES; ++t) {
    const unsigned char* Kc = (t & 1) ? KB : KA;
    const unsigned char* Ac = (t & 1) ? AB : AA;
    unsigned char* Kn = (t & 1) ? KA : KB;
    unsigned char* An = (t & 1) ? AA : AB;
    if (t < NTILES - 1) STAGEKA(t + 1, Kn, An);

    const unsigned short* vseg = vb + t * BK;

    // adj masks from LDS (staged last tile)
    int4 ad[2][2];
#pragma unroll
    for (int rg = 0; rg < 2; ++rg)
#pragma unroll
      for (int jt = 0; jt < 2; ++jt)
        ad[rg][jt] = *(const int4*)(Ac + abase + rg * 2048 + aswz[jt]);

    // ---- St = K·Q^T  (row = kv, col = q)
    f32x4 St[2][2];
#pragma unroll
    for (int jt = 0; jt < 2; ++jt) { St[0][jt] = z4; St[1][jt] = z4; }
#pragma unroll
    for (int jt = 0; jt < 2; ++jt)
#pragma unroll
      for (int kt = 0; kt < 8; ++kt) {
        bf16x8 kf = *(const bf16x8*)(Kc + kbase + jt * 8192 + cxor[kt]);
        St[0][jt] = __builtin_amdgcn_mfma_f32_16x16x32_bf16(kf, Qf[0][kt], St[0][jt], 0, 0, 0);
        St[1][jt] = __builtin_amdgcn_mfma_f32_16x16x32_bf16(kf, Qf[1][kt], St[1][jt], 0, 0, 0);
      }

    // ---- masked exp (fixed reference), pack to bf16 pairs
    unsigned pkA[2][2], pkB[2][2];
#pragma unroll
    for (int rg = 0; rg < 2; ++rg)
#pragma unroll
      for (int jt = 0; jt < 2; ++jt) {
        float e0 = exp2f(St[rg][jt][0] * SCALE);
        float e1 = exp2f(St[rg][jt][1] * SCALE);
        float e2 = exp2f(St[rg][jt][2] * SCALE);
        float e3 = exp2f(St[rg][jt][3] * SCALE);
        int4 m = ad[rg][jt];
        float v0 = m.x ? e0 : 0.f;
        float v1 = m.y ? e1 : 0.f;
        float v2 = m.z ? e2 : 0.f;
        float v3 = m.w ? e3 : 0.f;
        lp[rg] += (v0 + v1) + (v2 + v3);
        unsigned pA, pB;
        asm("v_cvt_pk_bf16_f32 %0, %1, %2" : "=v"(pA) : "v"(v0), "v"(v1));
        asm("v_cvt_pk_bf16_f32 %0, %1, %2" : "=v"(pB) : "v"(v2), "v"(v3));
        pkA[rg][jt] = pA;
        pkB[rg][jt] = pB;
      }

    // ---- cross-lane exchange: build A-fragment P[q=li][k=8g..8g+7]
    bf16x8 Pf[2];
#pragma unroll
    for (int rg = 0; rg < 2; ++rg) {
      unsigned A0 = pkA[rg][0], A1 = pkA[rg][1];
      unsigned B0 = pkB[rg][0], B1 = pkB[rg][1];
      unsigned sA0 = __shfl_xor(A0, 32), sA1 = __shfl_xor(A1, 32);
      unsigned sB0 = __shfl_xor(B0, 32), sB1 = __shfl_xor(B1, 32);
      unsigned UpA = lo32 ? A0 : sA1, VpA = lo32 ? sA0 : A1;
      unsigned UpB = lo32 ? B0 : sB1, VpB = lo32 ? sB0 : B1;
      unsigned xUA = __shfl_xor(UpA, 16), xVA = __shfl_xor(VpA, 16);
      unsigned xUB = __shfl_xor(UpB, 16), xVB = __shfl_xor(VpB, 16);
      union { unsigned u[4]; bf16x8 v; } pu;
      pu.u[0] = geven ? UpA : xVA;
      pu.u[1] = geven ? UpB : xVB;
      pu.u[2] = geven ? xUA : VpA;
      pu.u[3] = geven ? xUB : VpB;
      Pf[rg] = pu.v;
    }

    // ---- O += P V  (V direct from global/L2)
#pragma unroll
    for (int dt = 0; dt < 16; ++dt) {
      bf16x8 vf = *(const bf16x8*)(vseg + (size_t)dt * (16 * N_));
      O[0][dt] = __builtin_amdgcn_mfma_f32_16x16x32_bf16(Pf[0], vf, O[0][dt], 0, 0, 0);
      O[1][dt] = __builtin_amdgcn_mfma_f32_16x16x32_bf16(Pf[1], vf, O[1][dt], 0, 0, 0);
    }

    __syncthreads();
  }
#undef STAGEKA

  // ---- epilogue
#pragma unroll
  for (int rg = 0; rg < 2; ++rg) {
    float v = lp[rg];
    v += __shfl_xor(v, 16);
    v += __shfl_xor(v, 32);
    if (l < 16)
      lsum[(size_t)split * N_ + qrw + rg * 16 + li] = v;
  }
  const size_t ob = (size_t)split * N_ * OUTF_;
#pragma unroll
  for (int rg = 0; rg < 2; ++rg)
#pragma unroll
    for (int s = 0; s < 4; ++s) {
      unsigned short* op = Opart + ob + (size_t)(qrw + rg * 16 + 4 * g + s) * OUTF_ + li;
#pragma unroll
      for (int dt = 0; dt < 16; ++dt)
        op[dt * 16] = f2bf(O[rg][dt][s]);
    }
}

// ---------------------------------------------------------------------------
// Kernel 3: combine splits (plain sums), normalize, ELU.
// ---------------------------------------------------------------------------
__global__ __launch_bounds__(256) void k_combine(
    const unsigned short* __restrict__ Opart, const float* __restrict__ lsum,
    float* __restrict__ out)
{
  int idx = blockIdx.x * 256 + threadIdx.x;   // N*64 threads
  int row = idx >> 6;
  int c = (idx & 63) * 4;
  float L = 0.f, a0 = 0.f, a1 = 0.f, a2 = 0.f, a3 = 0.f;
#pragma unroll
  for (int s = 0; s < KVSPLIT; ++s) {
    L += lsum[(size_t)s * N_ + row];
    uint2 o = *(const uint2*)(Opart + ((size_t)s * N_ + row) * OUTF_ + c);
    a0 += bf2f((unsigned short)(o.x & 0xffff));
    a1 += bf2f((unsigned short)(o.x >> 16));
    a2 += bf2f((unsigned short)(o.y & 0xffff));
    a3 += bf2f((unsigned short)(o.y >> 16));
  }
  float inv = 1.f / L;
  float r0 = a0 * inv, r1 = a1 * inv, r2 = a2 * inv, r3 = a3 * inv;
  float4 r;
  r.x = r0 > 0.f ? r0 : expm1f(r0);
  r.y = r1 > 0.f ? r1 : expm1f(r1);
  r.z = r2 > 0.f ? r2 : expm1f(r2);
  r.w = r3 > 0.f ? r3 : expm1f(r3);
  *(float4*)(out + (size_t)row * OUTF_ + c) = r;
}

// ---------------------------------------------------------------------------
extern "C" void kernel_launch(void* const* d_in, const int* in_sizes, int n_in,
                              void* d_out, int out_size, void* d_ws, size_t ws_size,
                              hipStream_t stream) {
  const float* x  = (const float*)d_in[0];
  const int* adj  = (const int*)d_in[1];
  const float* W  = (const float*)d_in[2];
  const float* a  = (const float*)d_in[3];
  float* out = (float*)d_out;
  char* ws = (char*)d_ws;

  unsigned short* hK = (unsigned short*)(ws);                             // 0..4MB
  unsigned short* hT = (unsigned short*)(ws + (size_t)4 * 1024 * 1024);   // 4..8MB
  unsigned short* WT = (unsigned short*)(ws + (size_t)8 * 1024 * 1024);   // 8..9MB
  float* lsum = (float*)(ws + (size_t)9 * 1024 * 1024);                   // 9..10MB
  unsigned short* Opart = (unsigned short*)(ws + (size_t)10 * 1024 * 1024); // 10..42MB
  // xhi/xlo alias the Opart region (dead once k_gemm_h finishes)
  unsigned short* xhi = (unsigned short*)(ws + (size_t)10 * 1024 * 1024);
  unsigned short* xlo = (unsigned short*)(ws + (size_t)18 * 1024 * 1024);

  k_prep<<<(N_ * INF_ / 4) / 256, 256, 0, stream>>>(x, W, xhi, xlo, WT);
  dim3 g1(N_ / 64, OUTF_ / 64);
  k_gemm_h<<<g1, 256, 0, stream>>>(xhi, xlo, WT, hK, hT);
  k_attn<<<(N_ / BQ) * KVSPLIT, 256, 0, stream>>>(hK, hT, adj, a, Opart, lsum);
  k_combine<<<(N_ * 64) / 256, 256, 0, stream>>>(Opart, lsum, out);
}

// Round 6
// 161.070 us; speedup vs baseline: 1.7839x; 1.7839x over previous
//
#include <hip/hip_runtime.h>

#define N_ 8192
#define INF_ 512
#define OUTF_ 256
#define KVSPLIT 8
#define BK 32
#define BQ 128
#define NTILES (N_ / KVSPLIT / BK)   // 32

typedef float f32x4 __attribute__((ext_vector_type(4)));
typedef float f32x16 __attribute__((ext_vector_type(16)));
typedef __bf16 bf16x8 __attribute__((ext_vector_type(8)));

__device__ __forceinline__ unsigned short f2bf(float f) {
  union { float f; unsigned u; } v; v.f = f;
  unsigned r = v.u + 0x7fffu + ((v.u >> 16) & 1u);
  return (unsigned short)(r >> 16);
}
__device__ __forceinline__ float bf2f(unsigned short u) {
  union { unsigned u; float f; } v; v.u = ((unsigned)u) << 16;
  return v.f;
}

// ---------------------------------------------------------------------------
// Kernel 0: prep. x -> xhi+xlo (bf16 split), W -> WT (bf16, [col][k]).
// ---------------------------------------------------------------------------
__global__ __launch_bounds__(256) void k_prep(
    const float* __restrict__ x, const float* __restrict__ W,
    unsigned short* __restrict__ xhi, unsigned short* __restrict__ xlo,
    unsigned short* __restrict__ WT)
{
  int idx = blockIdx.x * 256 + threadIdx.x;     // 1M threads, one float4 each
  float4 v = ((const float4*)x)[idx];
  float f[4] = {v.x, v.y, v.z, v.w};
  unsigned short h[4], lo[4];
#pragma unroll
  for (int j = 0; j < 4; ++j) {
    h[j] = f2bf(f[j]);
    lo[j] = f2bf(f[j] - bf2f(h[j]));
  }
  *(uint2*)&xhi[idx * 4] = *(uint2*)h;
  *(uint2*)&xlo[idx * 4] = *(uint2*)lo;
  if (idx < INF_ * OUTF_) {
    int c = idx & (OUTF_ - 1);
    int k = idx >> 8;
    WT[c * INF_ + k] = f2bf(W[k * OUTF_ + c]);
  }
}

// ---------------------------------------------------------------------------
// Kernel 1: h = x @ W via bf16 MFMA (hi/lo split for x). No LDS.
// ---------------------------------------------------------------------------
__global__ __launch_bounds__(256) void k_gemm_h(
    const unsigned short* __restrict__ xhi, const unsigned short* __restrict__ xlo,
    const unsigned short* __restrict__ WT,
    unsigned short* __restrict__ hK, unsigned short* __restrict__ hT)
{
  const int tid = threadIdx.x;
  const int w = tid >> 6, l = tid & 63, g = l >> 4, li = l & 15;
  const int r0 = blockIdx.x * 64 + w * 16;
  const int c0 = blockIdx.y * 64;

  f32x4 acc[4];
  const f32x4 z4 = {0.f, 0.f, 0.f, 0.f};
#pragma unroll
  for (int n = 0; n < 4; ++n) acc[n] = z4;

  const unsigned short* xh = xhi + (size_t)(r0 + li) * INF_ + g * 8;
  const unsigned short* xl = xlo + (size_t)(r0 + li) * INF_ + g * 8;
  const unsigned short* wt = WT + (size_t)(c0 + li) * INF_ + g * 8;

#pragma unroll 4
  for (int kc = 0; kc < 16; ++kc) {
    bf16x8 Ah = *(const bf16x8*)(xh + kc * 32);
    bf16x8 Al = *(const bf16x8*)(xl + kc * 32);
#pragma unroll
    for (int n = 0; n < 4; ++n) {
      bf16x8 Bn = *(const bf16x8*)(wt + (size_t)n * 16 * INF_ + kc * 32);
      acc[n] = __builtin_amdgcn_mfma_f32_16x16x32_bf16(Ah, Bn, acc[n], 0, 0, 0);
      acc[n] = __builtin_amdgcn_mfma_f32_16x16x32_bf16(Al, Bn, acc[n], 0, 0, 0);
    }
  }
#pragma unroll
  for (int n = 0; n < 4; ++n)
#pragma unroll
    for (int s = 0; s < 4; ++s) {
      unsigned short b = f2bf(acc[n][s]);
      int row = r0 + 4 * g + s;
      int col = c0 + n * 16 + li;
      hK[(size_t)row * OUTF_ + col] = b;
      hT[(size_t)col * N_ + row] = b;
    }
}

// ---------------------------------------------------------------------------
// Kernel 2: fused masked attention, 32x32x16 MFMA.
//  - K, V^T in LDS (dbuf, gload_lds, XOR-swizzled via pre-swizzled source)
//  - adj as per-lane int4, register-prefetched one tile ahead
//  - swapped QK (St = K·Q^T), in-register P via cvt_pk + permlane32_swap
//  4 waves x 32 q-rows, BK=32, 64 KB LDS -> 2 blocks/CU.
// ---------------------------------------------------------------------------
__global__ __launch_bounds__(256, 2) void k_attn(
    const unsigned short* __restrict__ hK, const unsigned short* __restrict__ hT,
    const int* __restrict__ adj, const float* __restrict__ a,
    unsigned short* __restrict__ Opart, float* __restrict__ lsum)
{
  __shared__ __align__(16) unsigned char smem[65536];
  unsigned char* KA = smem;            // [32 kv][256 k] bf16, chunk^=(row&7)
  unsigned char* VA = smem + 16384;    // [256 d][32 kv] bf16, chunk^=( (d^(d>>2))&3 )
  unsigned char* KB = smem + 32768;
  unsigned char* VB = smem + 49152;

  const int tid = threadIdx.x;
  const int w = tid >> 6, l = tid & 63;
  const int q32 = l & 31;              // q-col (QK-D / PV-A row); also kv-row / d-col
  const int hi = l >> 5;
  const int bid = blockIdx.x;
  const int split = bid & 7;           // XCD-aligned KV split
  const int qblk = (bid >> 3) * BQ;
  const int qrw = qblk + w * 32;
  const int jb = split * (N_ / KVSPLIT);
  const float SCALE = 0.18033688011112042f;  // log2(e)/8

  // staging source offsets (16B chunks), LDS dest linear
  int offK[4], offV[4];
#pragma unroll
  for (int p = 0; p < 4; ++p) {
    int ch = tid + p * 256;
    int rK = ch >> 5, cK = ch & 31;
    offK[p] = rK * OUTF_ + ((cK ^ (rK & 7)) * 8);
    int dV = ch >> 2, cV = ch & 3;
    offV[p] = dV * N_ + ((cV ^ ((dV ^ (dV >> 2)) & 3)) * 8);
  }
  // K read addressing: row = q32 (kv), k-chunk (2kt+hi) ^ (row&7)
  const int kbase = q32 * 512;
  const int ehk = (hi ^ (q32 & 7)) << 4;
  // V read addressing: row d = dt*32+q32, chunk ((tt<<1)|hi) ^ sv
  const int sv = (q32 ^ (q32 >> 2)) & 3;
  const int c0v = (sv & 2) | (hi ^ (sv & 1));
  const int voff0 = q32 * 64 + (c0v << 4);

  // adj: lane-private row qrw+q32, kv cols 4*hi + {0,8,16,24} (+ t*32)
  const int* adjp = adj + (size_t)(qrw + q32) * N_ + jb + 4 * hi;

  // Q fragments: q-row = qrw+q32, k = kt*16 + 8*hi + j
  bf16x8 Qf[16];
  {
    const unsigned short* hp = hK + (size_t)(qrw + q32) * OUTF_;
#pragma unroll
    for (int kt = 0; kt < 16; ++kt) {
      const int off = kt * 16 + 8 * hi;
      bf16x8 hv = *(const bf16x8*)(hp + off);
      float4 a0 = *(const float4*)(a + off);
      float4 a1 = *(const float4*)(a + off + 4);
      bf16x8 q;
      q[0] = (__bf16)((float)hv[0] * a0.x);
      q[1] = (__bf16)((float)hv[1] * a0.y);
      q[2] = (__bf16)((float)hv[2] * a0.z);
      q[3] = (__bf16)((float)hv[3] * a0.w);
      q[4] = (__bf16)((float)hv[4] * a1.x);
      q[5] = (__bf16)((float)hv[5] * a1.y);
      q[6] = (__bf16)((float)hv[6] * a1.z);
      q[7] = (__bf16)((float)hv[7] * a1.w);
      Qf[kt] = q;
    }
  }

  f32x16 O[8];
#pragma unroll
  for (int dt = 0; dt < 8; ++dt)
#pragma unroll
    for (int r = 0; r < 16; ++r) O[dt][r] = 0.f;
  float lpv = 0.f;

#define STAGE(tt, Kd, Vd) do { \
    const unsigned short* _hk = hK + (size_t)(jb + (tt) * BK) * OUTF_; \
    const unsigned short* _ht = hT + (jb + (tt) * BK); \
    _Pragma("unroll") \
    for (int p = 0; p < 4; ++p) \
      __builtin_amdgcn_global_load_lds( \
        (const __attribute__((address_space(1))) void*)(_hk + offK[p]), \
        (__attribute__((address_space(3))) void*)((Kd) + (p * 256 + w * 64) * 16), 16, 0, 0); \
    _Pragma("unroll") \
    for (int p = 0; p < 4; ++p) \
      __builtin_amdgcn_global_load_lds( \
        (const __attribute__((address_space(1))) void*)(_ht + offV[p]), \
        (__attribute__((address_space(3))) void*)((Vd) + (p * 256 + w * 64) * 16), 16, 0, 0); \
  } while (0)

  int4 ad[4];
  STAGE(0, KA, VA);
#pragma unroll
  for (int i = 0; i < 4; ++i) ad[i] = *(const int4*)(adjp + i * 8);
  __syncthreads();

#pragma unroll 1
  for (int t = 0; t < NTILES; ++t) {
    const unsigned char* Kc = (t & 1) ? KB : KA;
    const unsigned char* Vc = (t & 1) ? VB : VA;
    unsigned char* Kn = (t & 1) ? KA : KB;
    unsigned char* Vn = (t & 1) ? VA : VB;
    if (t < NTILES - 1) STAGE(t + 1, Kn, Vn);

    // ---- St = K·Q^T : D col = q (lane&31), row = kv = (r&3)+8(r>>2)+4hi
    f32x16 St;
#pragma unroll
    for (int r = 0; r < 16; ++r) St[r] = 0.f;
#pragma unroll
    for (int kt = 0; kt < 16; ++kt) {
      bf16x8 kf = *(const bf16x8*)(Kc + kbase + ((kt << 5) ^ ehk));
      St = __builtin_amdgcn_mfma_f32_32x32x16_bf16(kf, Qf[kt], St, 0, 0, 0);
    }

    // ---- masked exp (fixed reference M=0), pack pairs; mask[r] = ad[r>>2][r&3]
    unsigned pk[8];
#pragma unroll
    for (int i = 0; i < 8; ++i) {
      int m0, m1;
      const int4 av = ad[i >> 1];
      if ((i & 1) == 0) { m0 = av.x; m1 = av.y; }
      else             { m0 = av.z; m1 = av.w; }
      float e0 = exp2f(St[2 * i]     * SCALE);
      float e1 = exp2f(St[2 * i + 1] * SCALE);
      float v0 = m0 ? e0 : 0.f;
      float v1 = m1 ? e1 : 0.f;
      lpv += v0 + v1;
      asm("v_cvt_pk_bf16_f32 %0, %1, %2" : "=v"(pk[i]) : "v"(v0), "v"(v1));
    }

    // ---- adj prefetch for t+1 (full-tile latency window)
    if (t + 1 < NTILES) {
#pragma unroll
      for (int i = 0; i < 4; ++i) ad[i] = *(const int4*)(adjp + (t + 1) * 32 + i * 8);
    }

    // ---- exchange: build A-frags P[q=lane&31][k = tt*16 + 8hi + j]
    bf16x8 Pf[2];
#pragma unroll
    for (int tt = 0; tt < 2; ++tt) {
      unsigned u0 = pk[4 * tt],     u2 = pk[4 * tt + 2];
      unsigned u1 = pk[4 * tt + 1], u3 = pk[4 * tt + 3];
      asm("v_permlane32_swap_b32 %0, %1" : "+v"(u0), "+v"(u2));
      asm("v_permlane32_swap_b32 %0, %1" : "+v"(u1), "+v"(u3));
      union { unsigned u[4]; bf16x8 v; } pu;
      pu.u[0] = u0; pu.u[1] = u1; pu.u[2] = u2; pu.u[3] = u3;
      Pf[tt] = pu.v;
    }

    // ---- O += P V  (D col = d-col, row = q)
#pragma unroll
    for (int dt = 0; dt < 8; ++dt) {
      bf16x8 v0 = *(const bf16x8*)(Vc + dt * 2048 + voff0);
      bf16x8 v1 = *(const bf16x8*)(Vc + dt * 2048 + (voff0 ^ 32));
      O[dt] = __builtin_amdgcn_mfma_f32_32x32x16_bf16(Pf[0], v0, O[dt], 0, 0, 0);
      O[dt] = __builtin_amdgcn_mfma_f32_32x32x16_bf16(Pf[1], v1, O[dt], 0, 0, 0);
    }

    __syncthreads();
  }
#undef STAGE

  // ---- epilogue
  {
    float lfull = lpv + __shfl_xor(lpv, 32);
    if (l < 32)
      lsum[(size_t)split * N_ + qrw + q32] = lfull;
  }
  const size_t ob = (size_t)split * N_ * OUTF_;
#pragma unroll
  for (int dt = 0; dt < 8; ++dt)
#pragma unroll
    for (int r = 0; r < 16; ++r) {
      int q = (r & 3) + 8 * (r >> 2) + 4 * hi;
      Opart[ob + (size_t)(qrw + q) * OUTF_ + dt * 32 + q32] = f2bf(O[dt][r]);
    }
}

// ---------------------------------------------------------------------------
// Kernel 3: combine splits (plain sums), normalize, ELU.
// ---------------------------------------------------------------------------
__global__ __launch_bounds__(256) void k_combine(
    const unsigned short* __restrict__ Opart, const float* __restrict__ lsum,
    float* __restrict__ out)
{
  int idx = blockIdx.x * 256 + threadIdx.x;   // N*64 threads
  int row = idx >> 6;
  int c = (idx & 63) * 4;
  float L = 0.f, a0 = 0.f, a1 = 0.f, a2 = 0.f, a3 = 0.f;
#pragma unroll
  for (int s = 0; s < KVSPLIT; ++s) {
    L += lsum[(size_t)s * N_ + row];
    uint2 o = *(const uint2*)(Opart + ((size_t)s * N_ + row) * OUTF_ + c);
    a0 += bf2f((unsigned short)(o.x & 0xffff));
    a1 += bf2f((unsigned short)(o.x >> 16));
    a2 += bf2f((unsigned short)(o.y & 0xffff));
    a3 += bf2f((unsigned short)(o.y >> 16));
  }
  float inv = 1.f / L;
  float r0 = a0 * inv, r1 = a1 * inv, r2 = a2 * inv, r3 = a3 * inv;
  float4 r;
  r.x = r0 > 0.f ? r0 : expm1f(r0);
  r.y = r1 > 0.f ? r1 : expm1f(r1);
  r.z = r2 > 0.f ? r2 : expm1f(r2);
  r.w = r3 > 0.f ? r3 : expm1f(r3);
  *(float4*)(out + (size_t)row * OUTF_ + c) = r;
}

// ---------------------------------------------------------------------------
extern "C" void kernel_launch(void* const* d_in, const int* in_sizes, int n_in,
                              void* d_out, int out_size, void* d_ws, size_t ws_size,
                              hipStream_t stream) {
  const float* x  = (const float*)d_in[0];
  const int* adj  = (const int*)d_in[1];
  const float* W  = (const float*)d_in[2];
  const float* a  = (const float*)d_in[3];
  float* out = (float*)d_out;
  char* ws = (char*)d_ws;

  unsigned short* hK = (unsigned short*)(ws);                             // 0..4MB
  unsigned short* hT = (unsigned short*)(ws + (size_t)4 * 1024 * 1024);   // 4..8MB
  unsigned short* WT = (unsigned short*)(ws + (size_t)8 * 1024 * 1024);   // 8..9MB
  float* lsum = (float*)(ws + (size_t)9 * 1024 * 1024);                   // 9..10MB
  unsigned short* Opart = (unsigned short*)(ws + (size_t)10 * 1024 * 1024); // 10..42MB
  // xhi/xlo alias the Opart region (dead once k_gemm_h finishes)
  unsigned short* xhi = (unsigned short*)(ws + (size_t)10 * 1024 * 1024);
  unsigned short* xlo = (unsigned short*)(ws + (size_t)18 * 1024 * 1024);

  k_prep<<<(N_ * INF_ / 4) / 256, 256, 0, stream>>>(x, W, xhi, xlo, WT);
  dim3 g1(N_ / 64, OUTF_ / 64);
  k_gemm_h<<<g1, 256, 0, stream>>>(xhi, xlo, WT, hK, hT);
  k_attn<<<(N_ / BQ) * KVSPLIT, 256, 0, stream>>>(hK, hT, adj, a, Opart, lsum);
  k_combine<<<(N_ * 64) / 256, 256, 0, stream>>>(Opart, lsum, out);
}